// Round 8
// baseline (336.108 us; speedup 1.0000x reference)
//
#include <hip/hip_runtime.h>
#include <hip/hip_bf16.h>

#define DELTA 0.05f

typedef __attribute__((ext_vector_type(8))) short short8;
typedef __attribute__((ext_vector_type(4))) float f32x4;

__device__ __forceinline__ unsigned short tern_bits(float v) {
    return v > DELTA ? 0x3F80u : (v < -DELTA ? 0xBF80u : 0u);
}

__device__ __forceinline__ short f32_to_bf16_bits(float v) {
    __hip_bfloat16 h = __float2bfloat16(v);
    unsigned short bits;
    __builtin_memcpy(&bits, &h, 2);
    return (short)bits;
}

// ---------------- quantize x -> ternary bf16 ----------------
__global__ void quant_a_kernel(const float* __restrict__ x,
                               unsigned short* __restrict__ out, long total) {
    long idx = ((long)blockIdx.x * blockDim.x + threadIdx.x) * 8;
    long stride = (long)gridDim.x * blockDim.x * 8;
    for (; idx < total; idx += stride) {
        const float4* p = reinterpret_cast<const float4*>(x + idx);
        float4 v0 = p[0], v1 = p[1];
        short8 r;
        r[0] = (short)tern_bits(v0.x); r[1] = (short)tern_bits(v0.y);
        r[2] = (short)tern_bits(v0.z); r[3] = (short)tern_bits(v0.w);
        r[4] = (short)tern_bits(v1.x); r[5] = (short)tern_bits(v1.y);
        r[6] = (short)tern_bits(v1.z); r[7] = (short)tern_bits(v1.w);
        *reinterpret_cast<short8*>(out + idx) = r;
    }
}

// ---------------- quantize w_latent -> w_eff bf16 ----------------
__global__ void quant_w_kernel(const float* __restrict__ w,
                               const float* __restrict__ ap,
                               const float* __restrict__ an,
                               unsigned short* __restrict__ out,
                               int K, long total) {
    long idx = ((long)blockIdx.x * blockDim.x + threadIdx.x) * 8;
    long stride = (long)gridDim.x * blockDim.x * 8;
    for (; idx < total; idx += stride) {
        int n = (int)(idx / K);
        float pv = ap[n], nv = -an[n];
        const float4* p = reinterpret_cast<const float4*>(w + idx);
        float4 v0 = p[0], v1 = p[1];
        float vals[8] = {v0.x, v0.y, v0.z, v0.w, v1.x, v1.y, v1.z, v1.w};
        short8 r;
#pragma unroll
        for (int e = 0; e < 8; ++e) {
            float v = vals[e];
            float ev = v > DELTA ? pv : (v < -DELTA ? nv : 0.0f);
            r[e] = f32_to_bf16_bits(ev);
        }
        *reinterpret_cast<short8*>(out + idx) = r;
    }
}

// ================= 256x256x64 8-phase GEMM (r6 + RACE-FIXED prefetch) ========
// vs round-7 (raced, absmax 32): vmcnt(N) is PER-WAVE, so cross-buffer
// prefetch reads (Q0 + B of the newly-landed tile) must come AFTER the gate's
// s_barrier (which globalizes "my stages landed" -> "all stages landed").
// Gate is now: MF(3); vmcnt(6); BAR; LDA(Q0'); LDBF'.  Within-buffer Q1/Q2/Q3
// prefetches (data landed at the PREVIOUS gate+barrier) stay overlapped with
// the preceding MFMA cluster, as in round-7.
__global__ __launch_bounds__(512, 1) void gemm8p(
    const unsigned short* __restrict__ A, const unsigned short* __restrict__ B,
    const float* __restrict__ bias, float* __restrict__ C,
    int M, int N, int K) {
    __shared__ unsigned short As[2 * 256 * 64];
    __shared__ unsigned short Bs[2 * 256 * 64];

    const int tid = threadIdx.x;
    const int wid = tid >> 6;
    const int ln  = tid & 63;
    const int wr  = wid >> 2;   // 0..1
    const int wc  = wid & 3;    // 0..3

    // --- XCD-chunked swizzle (bijective: nwg % 8 == 0 when gridDim.y % 8 == 0)
    int bx = blockIdx.x, by = blockIdx.y;
    if ((gridDim.y & 7) == 0) {
        const int nbx = gridDim.x;
        const int rpx = gridDim.y >> 3;       // rows per XCD chunk
        int bid = by * nbx + bx;
        int xcd = bid & 7;
        int off = bid >> 3;
        by = xcd * rpx + (off % rpx);         // row fastest within chunk
        bx = off / rpx;
    }
    const int brow = by * 256;
    const int bcol = bx * 256;

    const int NT   = K >> 6;    // K/64 tiles
    const int STOT = NT * 4;    // half-tile stream length

    // staging geometry: chunk = 8 rows x 64 cols (1 KiB), 2 chunks/wave/half-tile
    const int srow   = ln >> 3;
    const int scol   = ((ln & 7) ^ srow) * 8;   // inverse-swizzled source col
    const int chunk0 = wid * 2;

    // ds_read geometry
    const int lnlo = ln & 15;
    const int swz  = (ln & 7) << 4;
    const int koff = (ln >> 4) * 16;

    f32x4 acc[8][4] = {};
    short8 bfrag[4][2];
    short8 af0[2][2], af1[2][2];
    int s = 0;

    auto STAGE = [&](int si) {
        if (si >= STOT) return;
        int tile = si >> 2, slot = si & 3, buf = tile & 1;
        int kt = tile << 6;
        const unsigned short* g = (slot >= 2) ? A : B;
        int grow = ((slot >= 2) ? brow : bcol) + (slot & 1) * 128;
        unsigned short* lb = ((slot >= 2) ? As : Bs) + buf * 16384 + (slot & 1) * 8192;
#pragma unroll
        for (int j = 0; j < 2; ++j) {
            int c = chunk0 + j;
            const unsigned short* src =
                g + (size_t)(grow + c * 8 + srow) * K + kt + scol;
            __builtin_amdgcn_global_load_lds(
                (const __attribute__((address_space(1))) void*)src,
                (__attribute__((address_space(3))) void*)(lb + c * 512),
                16, 0, 0);
        }
    };

#define LDA(DST, BUF, Q)                                                       \
    {                                                                          \
        const char* Ab = (const char*)As + (BUF) * 32768;                      \
        _Pragma("unroll")                                                      \
        for (int m2 = 0; m2 < 2; ++m2) {                                       \
            int r = wr * 128 + ((Q) * 2 + m2) * 16 + lnlo;                     \
            _Pragma("unroll")                                                  \
            for (int kk = 0; kk < 2; ++kk)                                     \
                DST[m2][kk] = *(const short8*)(Ab + r * 128 +                  \
                                               ((kk * 64 + koff) ^ swz));      \
        }                                                                      \
    }
#define LDBF(BUF)                                                              \
    {                                                                          \
        const char* Bb = (const char*)Bs + (BUF) * 32768;                      \
        _Pragma("unroll")                                                      \
        for (int n = 0; n < 4; ++n) {                                          \
            int r = wc * 64 + n * 16 + lnlo;                                   \
            _Pragma("unroll")                                                  \
            for (int kk = 0; kk < 2; ++kk)                                     \
                bfrag[n][kk] = *(const short8*)(Bb + r * 128 +                 \
                                                ((kk * 64 + koff) ^ swz));     \
        }                                                                      \
    }
#define MF(Q, AF)                                                              \
    __builtin_amdgcn_s_setprio(1);                                             \
    _Pragma("unroll")                                                          \
    for (int m2 = 0; m2 < 2; ++m2)                                             \
        _Pragma("unroll")                                                      \
        for (int n = 0; n < 4; ++n)                                            \
            _Pragma("unroll")                                                  \
            for (int kk = 0; kk < 2; ++kk)                                     \
                acc[(Q) * 2 + m2][n] = __builtin_amdgcn_mfma_f32_16x16x32_bf16(\
                    AF[m2][kk], bfrag[n][kk], acc[(Q) * 2 + m2][n], 0, 0, 0);  \
    __builtin_amdgcn_s_setprio(0);
#define BAR() __builtin_amdgcn_s_barrier()
#define VMC6() asm volatile("s_waitcnt vmcnt(6)" ::: "memory")
#define VMC0() asm volatile("s_waitcnt vmcnt(0)" ::: "memory")

    // ---- prologue: stage 7 half-tiles; gate T0; reads AFTER the barrier ----
    for (int i = 0; i < 7; ++i) { STAGE(s); ++s; }
    VMC6();
    BAR();
    LDA(af0, 0, 0)
    LDBF(0)

    const int NP = NT / 2 - 1;
#pragma unroll 1
    for (int p = 0; p < NP; ++p) {
        // ph1 (buf0 Q0)
        STAGE(s); ++s; BAR();
        LDA(af1, 0, 1)
        MF(0, af0)
        BAR();
        // ph2 (buf0 Q1)
        STAGE(s); ++s; BAR();
        LDA(af0, 0, 2)
        MF(1, af1)
        BAR();
        // ph3 (buf0 Q2)
        STAGE(s); ++s; BAR();
        LDA(af1, 0, 3)
        MF(2, af0)
        BAR();
        // ph4 (buf0 Q3): gate T+1, then post-barrier prefetch of buf1 Q0 + B
        STAGE(s); ++s; BAR();
        MF(3, af1)
        VMC6();
        BAR();
        LDA(af0, 1, 0)
        LDBF(1)
        // ph5 (buf1 Q0)
        STAGE(s); ++s; BAR();
        LDA(af1, 1, 1)
        MF(0, af0)
        BAR();
        // ph6 (buf1 Q1)
        STAGE(s); ++s; BAR();
        LDA(af0, 1, 2)
        MF(1, af1)
        BAR();
        // ph7 (buf1 Q2)
        STAGE(s); ++s; BAR();
        LDA(af1, 1, 3)
        MF(2, af0)
        BAR();
        // ph8 (buf1 Q3): gate T+2, then post-barrier prefetch of buf0 Q0 + B
        STAGE(s); ++s; BAR();
        MF(3, af1)
        VMC6();
        BAR();
        LDA(af0, 0, 0)
        LDBF(0)
    }

    // ---- epilogue: tiles NT-2 (buf0), NT-1 (buf1) ----
    // T_{NT-2} ph1: stage the final half-tile (T_{NT-1} A.h1 -> buf1)
    STAGE(s); ++s; BAR();
    LDA(af1, 0, 1)
    MF(0, af0)
    BAR();
    // ph2
    BAR();
    LDA(af0, 0, 2)
    MF(1, af1)
    BAR();
    // ph3
    BAR();
    LDA(af1, 0, 3)
    MF(2, af0)
    BAR();
    // ph4: drain ALL stages, then post-barrier prefetch of buf1 (T_{NT-1})
    BAR();
    MF(3, af1)
    VMC0();
    BAR();
    LDA(af0, 1, 0)
    LDBF(1)
    // T_{NT-1} ph1..ph4 (no stages)
    BAR();
    LDA(af1, 1, 1)
    MF(0, af0)
    BAR();
    BAR();
    LDA(af0, 1, 2)
    MF(1, af1)
    BAR();
    BAR();
    LDA(af1, 1, 3)
    MF(2, af0)
    BAR();
    BAR();
    MF(3, af1)

#undef LDA
#undef LDBF
#undef MF
#undef BAR
#undef VMC6
#undef VMC0

    // C write + bias. D layout: col=lane&15, row=(lane>>4)*4+q
#pragma unroll
    for (int n = 0; n < 4; ++n) {
        int col = bcol + wc * 64 + n * 16 + lnlo;
        float bv = bias[col];
#pragma unroll
        for (int m = 0; m < 8; ++m) {
            int row0 = brow + wr * 128 + m * 16 + (ln >> 4) * 4;
#pragma unroll
            for (int q = 0; q < 4; ++q)
                C[(size_t)(row0 + q) * N + col] = acc[m][n][q] + bv;
        }
    }
}

// ---------------- fallback 128^2 GEMM (round-1, known-good) ----------------
template <int MODE>
__global__ __launch_bounds__(256) void gemm_tern(
    const unsigned short* __restrict__ A, const unsigned short* __restrict__ B,
    const float* __restrict__ Xf, const float* __restrict__ Wf,
    const float* __restrict__ alpha_p, const float* __restrict__ alpha_n,
    const float* __restrict__ bias, float* __restrict__ C,
    int M, int N, int K) {
    __shared__ unsigned short As[128 * 32];
    __shared__ unsigned short Bs[128 * 32];

    const int tid = threadIdx.x;
    const int wv = tid >> 6;
    const int ln = tid & 63;
    const int brow = blockIdx.y * 128;
    const int bcol = blockIdx.x * 128;
    const int wr = wv >> 1;
    const int wc = wv & 1;

    f32x4 acc[4][4] = {};

    for (int kt = 0; kt < K; kt += 32) {
        if (MODE == 0) {
#pragma unroll
            for (int j = 0; j < 2; ++j) {
                int chunk = wv * 2 + j;
                int r = chunk * 16 + (ln >> 2);
                int kc = (ln & 3) * 8;
                const unsigned short* ga = A + (size_t)(brow + r) * K + kt + kc;
                const unsigned short* gb = B + (size_t)(bcol + r) * K + kt + kc;
                __builtin_amdgcn_global_load_lds(
                    (const __attribute__((address_space(1))) void*)ga,
                    (__attribute__((address_space(3))) void*)(As + chunk * 512),
                    16, 0, 0);
                __builtin_amdgcn_global_load_lds(
                    (const __attribute__((address_space(1))) void*)gb,
                    (__attribute__((address_space(3))) void*)(Bs + chunk * 512),
                    16, 0, 0);
            }
        } else {
#pragma unroll
            for (int j = 0; j < 2; ++j) {
                int chunk = wv * 2 + j;
                int r = chunk * 16 + (ln >> 2);
                int kc = (ln & 3) * 8;
                const float4* xa =
                    reinterpret_cast<const float4*>(Xf + (size_t)(brow + r) * K + kt + kc);
                float4 a0 = xa[0], a1 = xa[1];
                short8 ta;
                ta[0] = (short)tern_bits(a0.x); ta[1] = (short)tern_bits(a0.y);
                ta[2] = (short)tern_bits(a0.z); ta[3] = (short)tern_bits(a0.w);
                ta[4] = (short)tern_bits(a1.x); ta[5] = (short)tern_bits(a1.y);
                ta[6] = (short)tern_bits(a1.z); ta[7] = (short)tern_bits(a1.w);
                *reinterpret_cast<short8*>(As + chunk * 512 + ln * 8) = ta;

                int rn = bcol + r;
                float pv = alpha_p[rn], nv = -alpha_n[rn];
                const float4* wb =
                    reinterpret_cast<const float4*>(Wf + (size_t)rn * K + kt + kc);
                float4 b0 = wb[0], b1 = wb[1];
                float vals[8] = {b0.x, b0.y, b0.z, b0.w, b1.x, b1.y, b1.z, b1.w};
                short8 tb;
#pragma unroll
                for (int e = 0; e < 8; ++e) {
                    float v = vals[e];
                    float ev = v > DELTA ? pv : (v < -DELTA ? nv : 0.0f);
                    tb[e] = f32_to_bf16_bits(ev);
                }
                *reinterpret_cast<short8*>(Bs + chunk * 512 + ln * 8) = tb;
            }
        }
        __syncthreads();

        short8 af[4], bfr[4];
#pragma unroll
        for (int i = 0; i < 4; ++i) {
            int ra = wr * 64 + i * 16 + (ln & 15);
            af[i] = *reinterpret_cast<const short8*>(As + ra * 32 + (ln >> 4) * 8);
            int rb = wc * 64 + i * 16 + (ln & 15);
            bfr[i] = *reinterpret_cast<const short8*>(Bs + rb * 32 + (ln >> 4) * 8);
        }
#pragma unroll
        for (int i = 0; i < 4; ++i)
#pragma unroll
            for (int j = 0; j < 4; ++j)
                acc[i][j] = __builtin_amdgcn_mfma_f32_16x16x32_bf16(
                    af[i], bfr[j], acc[i][j], 0, 0, 0);
        __syncthreads();
    }

#pragma unroll
    for (int j = 0; j < 4; ++j) {
        int col = bcol + wc * 64 + j * 16 + (ln & 15);
        float bv = bias[col];
#pragma unroll
        for (int i = 0; i < 4; ++i) {
            int row0 = brow + wr * 64 + i * 16 + (ln >> 4) * 4;
#pragma unroll
            for (int q = 0; q < 4; ++q) {
                C[(size_t)(row0 + q) * N + col] = acc[i][j][q] + bv;
            }
        }
    }
}

extern "C" void kernel_launch(void* const* d_in, const int* in_sizes, int n_in,
                              void* d_out, int out_size, void* d_ws, size_t ws_size,
                              hipStream_t stream) {
    const float* x  = (const float*)d_in[0];
    const float* w  = (const float*)d_in[1];
    const float* ap = (const float*)d_in[2];
    const float* an = (const float*)d_in[3];
    const float* bs = (const float*)d_in[4];
    float* out = (float*)d_out;

    const int N = in_sizes[2];            // 4096
    const int K = in_sizes[1] / N;        // 4096
    const int M = in_sizes[0] / K;        // 8192

    const size_t needA = (size_t)M * K * 2;
    const size_t needB = (size_t)N * K * 2;

    if (ws_size >= needA + needB) {
        unsigned short* aq = (unsigned short*)d_ws;
        unsigned short* wq = (unsigned short*)((char*)d_ws + needA);
        quant_a_kernel<<<2048, 256, 0, stream>>>(x, aq, (long)M * K);
        quant_w_kernel<<<2048, 256, 0, stream>>>(w, ap, an, wq, K, (long)N * K);
        const bool ok8p = (M % 256 == 0) && (N % 256 == 0) && (K % 128 == 0) && (K >= 256);
        if (ok8p) {
            dim3 grid(N / 256, M / 256);
            gemm8p<<<grid, 512, 0, stream>>>(aq, wq, bs, out, M, N, K);
        } else {
            dim3 grid(N / 128, M / 128);
            gemm_tern<0><<<grid, 256, 0, stream>>>(aq, wq, nullptr, nullptr,
                                                   ap, an, bs, out, M, N, K);
        }
    } else {
        dim3 grid(N / 128, M / 128);
        gemm_tern<1><<<grid, 256, 0, stream>>>(nullptr, nullptr, x, w,
                                               ap, an, bs, out, M, N, K);
    }
}

// Round 9
// 328.496 us; speedup vs baseline: 1.0232x; 1.0232x over previous
//
#include <hip/hip_runtime.h>
#include <hip/hip_bf16.h>

#define DELTA 0.05f

typedef __attribute__((ext_vector_type(8))) short short8;
typedef __attribute__((ext_vector_type(4))) float f32x4;

__device__ __forceinline__ unsigned short tern_bits(float v) {
    return v > DELTA ? 0x3F80u : (v < -DELTA ? 0xBF80u : 0u);
}

__device__ __forceinline__ short f32_to_bf16_bits(float v) {
    __hip_bfloat16 h = __float2bfloat16(v);
    unsigned short bits;
    __builtin_memcpy(&bits, &h, 2);
    return (short)bits;
}

// ---------------- fused quantize: blocks [0,AB) do x, [AB,AB+WB) do w -------
__global__ void quant_ab_kernel(const float* __restrict__ x,
                                const float* __restrict__ w,
                                const float* __restrict__ ap,
                                const float* __restrict__ an,
                                unsigned short* __restrict__ aq,
                                unsigned short* __restrict__ wq,
                                int K, long totalA, long totalW, int ABLK) {
    if ((int)blockIdx.x < ABLK) {
        long idx = ((long)blockIdx.x * blockDim.x + threadIdx.x) * 8;
        long stride = (long)ABLK * blockDim.x * 8;
        for (; idx < totalA; idx += stride) {
            const float4* p = reinterpret_cast<const float4*>(x + idx);
            float4 v0 = p[0], v1 = p[1];
            short8 r;
            r[0] = (short)tern_bits(v0.x); r[1] = (short)tern_bits(v0.y);
            r[2] = (short)tern_bits(v0.z); r[3] = (short)tern_bits(v0.w);
            r[4] = (short)tern_bits(v1.x); r[5] = (short)tern_bits(v1.y);
            r[6] = (short)tern_bits(v1.z); r[7] = (short)tern_bits(v1.w);
            *reinterpret_cast<short8*>(aq + idx) = r;
        }
    } else {
        int wb = (int)blockIdx.x - ABLK;
        int nwb = (int)gridDim.x - ABLK;
        long idx = ((long)wb * blockDim.x + threadIdx.x) * 8;
        long stride = (long)nwb * blockDim.x * 8;
        for (; idx < totalW; idx += stride) {
            int n = (int)(idx / K);
            float pv = ap[n], nv = -an[n];
            const float4* p = reinterpret_cast<const float4*>(w + idx);
            float4 v0 = p[0], v1 = p[1];
            float vals[8] = {v0.x, v0.y, v0.z, v0.w, v1.x, v1.y, v1.z, v1.w};
            short8 r;
#pragma unroll
            for (int e = 0; e < 8; ++e) {
                float v = vals[e];
                float ev = v > DELTA ? pv : (v < -DELTA ? nv : 0.0f);
                r[e] = f32_to_bf16_bits(ev);
            }
            *reinterpret_cast<short8*>(wq + idx) = r;
        }
    }
}

// ================= 256x256x64 8-phase GEMM (round-6 verbatim, K templated) ===
// Round-6 K-loop byte-for-byte (248.5us / 47.3% MfmaUtil / 0 conflicts).
// ONLY change: K is a compile-time template parameter -> all staging and
// fragment address arithmetic folds to shifts + immediates (the STAGE lambda's
// runtime (row*K) multiply was serial pre-barrier VALU every phase).
template <int KC>
__global__ __launch_bounds__(512, 2) void gemm8p(
    const unsigned short* __restrict__ A, const unsigned short* __restrict__ B,
    const float* __restrict__ bias, float* __restrict__ C,
    int M, int N) {
    __shared__ unsigned short As[2 * 256 * 64];
    __shared__ unsigned short Bs[2 * 256 * 64];

    const int tid = threadIdx.x;
    const int wid = tid >> 6;
    const int ln  = tid & 63;
    const int wr  = wid >> 2;   // 0..1
    const int wc  = wid & 3;    // 0..3

    // --- XCD-chunked swizzle (bijective: nwg % 8 == 0 when gridDim.y % 8 == 0)
    int bx = blockIdx.x, by = blockIdx.y;
    if ((gridDim.y & 7) == 0) {
        const int nbx = gridDim.x;
        const int rpx = gridDim.y >> 3;       // rows per XCD chunk
        int bid = by * nbx + bx;
        int xcd = bid & 7;
        int off = bid >> 3;
        by = xcd * rpx + (off % rpx);         // row fastest within chunk
        bx = off / rpx;
    }
    const int brow = by * 256;
    const int bcol = bx * 256;

    const int NT   = KC >> 6;   // K/64 tiles
    const int STOT = NT * 4;    // half-tile stream length

    // staging geometry: chunk = 8 rows x 64 cols (1 KiB), 2 chunks/wave/half-tile
    const int srow   = ln >> 3;
    const int scol   = ((ln & 7) ^ srow) * 8;   // inverse-swizzled source col
    const int chunk0 = wid * 2;

    // ds_read geometry
    const int lnlo = ln & 15;
    const int swz  = (ln & 7) << 4;
    const int koff = (ln >> 4) * 16;

    f32x4 acc[8][4] = {};
    short8 bfrag[4][2];
    int s = 0;

    auto STAGE = [&](int si) {
        if (si >= STOT) return;
        int tile = si >> 2, slot = si & 3, buf = tile & 1;
        int kt = tile << 6;
        const unsigned short* g = (slot >= 2) ? A : B;
        int grow = ((slot >= 2) ? brow : bcol) + (slot & 1) * 128;
        unsigned short* lb = ((slot >= 2) ? As : Bs) + buf * 16384 + (slot & 1) * 8192;
#pragma unroll
        for (int j = 0; j < 2; ++j) {
            int c = chunk0 + j;
            const unsigned short* src =
                g + (size_t)(grow + c * 8 + srow) * KC + kt + scol;
            __builtin_amdgcn_global_load_lds(
                (const __attribute__((address_space(1))) void*)src,
                (__attribute__((address_space(3))) void*)(lb + c * 512),
                16, 0, 0);
        }
    };

#define PHASE(BUF, Q, FIRST, VMS)                                              \
    {                                                                          \
        const char* Ab = (const char*)As + (BUF) * 32768;                      \
        const char* Bb = (const char*)Bs + (BUF) * 32768;                      \
        short8 afrag[2][2];                                                    \
        _Pragma("unroll")                                                      \
        for (int m2 = 0; m2 < 2; ++m2) {                                       \
            int r = wr * 128 + ((Q) * 2 + m2) * 16 + lnlo;                     \
            _Pragma("unroll")                                                  \
            for (int kk = 0; kk < 2; ++kk)                                     \
                afrag[m2][kk] = *(const short8*)(Ab + r * 128 +                \
                                                 ((kk * 64 + koff) ^ swz));    \
        }                                                                      \
        if (FIRST) {                                                           \
            _Pragma("unroll")                                                  \
            for (int n = 0; n < 4; ++n) {                                      \
                int r = wc * 64 + n * 16 + lnlo;                               \
                _Pragma("unroll")                                              \
                for (int kk = 0; kk < 2; ++kk)                                 \
                    bfrag[n][kk] = *(const short8*)(Bb + r * 128 +             \
                                                    ((kk * 64 + koff) ^ swz)); \
            }                                                                  \
        }                                                                      \
        STAGE(s); ++s;                                                         \
        __builtin_amdgcn_s_barrier();                                          \
        asm volatile("s_waitcnt lgkmcnt(0)");                                  \
        __builtin_amdgcn_s_setprio(1);                                         \
        _Pragma("unroll")                                                      \
        for (int m2 = 0; m2 < 2; ++m2)                                         \
            _Pragma("unroll")                                                  \
            for (int n = 0; n < 4; ++n)                                        \
                _Pragma("unroll")                                              \
                for (int kk = 0; kk < 2; ++kk)                                 \
                    acc[(Q) * 2 + m2][n] =                                     \
                        __builtin_amdgcn_mfma_f32_16x16x32_bf16(               \
                            afrag[m2][kk], bfrag[n][kk],                       \
                            acc[(Q) * 2 + m2][n], 0, 0, 0);                    \
        __builtin_amdgcn_s_setprio(0);                                         \
        VMS;                                                                   \
        __builtin_amdgcn_s_barrier();                                          \
    }

    // prologue: t0 fully (4 ht) + 3 ht of t1; gate t0
    for (int i = 0; i < 7; ++i) { STAGE(s); ++s; }
    asm volatile("s_waitcnt vmcnt(6)" ::: "memory");
    __builtin_amdgcn_s_barrier();

    const int NP = NT / 2 - 1;
#pragma unroll 1
    for (int p = 0; p < NP; ++p) {
        PHASE(0, 0, true,  (void)0)
        PHASE(0, 1, false, (void)0)
        PHASE(0, 2, false, (void)0)
        PHASE(0, 3, false, asm volatile("s_waitcnt vmcnt(6)" ::: "memory"))
        PHASE(1, 0, true,  (void)0)
        PHASE(1, 1, false, (void)0)
        PHASE(1, 2, false, (void)0)
        PHASE(1, 3, false, asm volatile("s_waitcnt vmcnt(6)" ::: "memory"))
    }
    // epilogue tiles NT-2 (buf0), NT-1 (buf1)
    PHASE(0, 0, true,  (void)0)
    PHASE(0, 1, false, (void)0)
    PHASE(0, 2, false, (void)0)
    PHASE(0, 3, false, asm volatile("s_waitcnt vmcnt(0)" ::: "memory"))
    PHASE(1, 0, true,  (void)0)
    PHASE(1, 1, false, (void)0)
    PHASE(1, 2, false, (void)0)
    PHASE(1, 3, false, (void)0)
#undef PHASE

    // C write + bias. D layout: col=lane&15, row=(lane>>4)*4+q
#pragma unroll
    for (int n = 0; n < 4; ++n) {
        int col = bcol + wc * 64 + n * 16 + lnlo;
        float bv = bias[col];
#pragma unroll
        for (int m = 0; m < 8; ++m) {
            int row0 = brow + wr * 128 + m * 16 + (ln >> 4) * 4;
#pragma unroll
            for (int q = 0; q < 4; ++q)
                C[(size_t)(row0 + q) * N + col] = acc[m][n][q] + bv;
        }
    }
}

// ---------------- fallback 128^2 GEMM (round-1, known-good) ----------------
template <int MODE>
__global__ __launch_bounds__(256) void gemm_tern(
    const unsigned short* __restrict__ A, const unsigned short* __restrict__ B,
    const float* __restrict__ Xf, const float* __restrict__ Wf,
    const float* __restrict__ alpha_p, const float* __restrict__ alpha_n,
    const float* __restrict__ bias, float* __restrict__ C,
    int M, int N, int K) {
    __shared__ unsigned short As[128 * 32];
    __shared__ unsigned short Bs[128 * 32];

    const int tid = threadIdx.x;
    const int wv = tid >> 6;
    const int ln = tid & 63;
    const int brow = blockIdx.y * 128;
    const int bcol = blockIdx.x * 128;
    const int wr = wv >> 1;
    const int wc = wv & 1;

    f32x4 acc[4][4] = {};

    for (int kt = 0; kt < K; kt += 32) {
        if (MODE == 0) {
#pragma unroll
            for (int j = 0; j < 2; ++j) {
                int chunk = wv * 2 + j;
                int r = chunk * 16 + (ln >> 2);
                int kc = (ln & 3) * 8;
                const unsigned short* ga = A + (size_t)(brow + r) * K + kt + kc;
                const unsigned short* gb = B + (size_t)(bcol + r) * K + kt + kc;
                __builtin_amdgcn_global_load_lds(
                    (const __attribute__((address_space(1))) void*)ga,
                    (__attribute__((address_space(3))) void*)(As + chunk * 512),
                    16, 0, 0);
                __builtin_amdgcn_global_load_lds(
                    (const __attribute__((address_space(1))) void*)gb,
                    (__attribute__((address_space(3))) void*)(Bs + chunk * 512),
                    16, 0, 0);
            }
        } else {
#pragma unroll
            for (int j = 0; j < 2; ++j) {
                int chunk = wv * 2 + j;
                int r = chunk * 16 + (ln >> 2);
                int kc = (ln & 3) * 8;
                const float4* xa =
                    reinterpret_cast<const float4*>(Xf + (size_t)(brow + r) * K + kt + kc);
                float4 a0 = xa[0], a1 = xa[1];
                short8 ta;
                ta[0] = (short)tern_bits(a0.x); ta[1] = (short)tern_bits(a0.y);
                ta[2] = (short)tern_bits(a0.z); ta[3] = (short)tern_bits(a0.w);
                ta[4] = (short)tern_bits(a1.x); ta[5] = (short)tern_bits(a1.y);
                ta[6] = (short)tern_bits(a1.z); ta[7] = (short)tern_bits(a1.w);
                *reinterpret_cast<short8*>(As + chunk * 512 + ln * 8) = ta;

                int rn = bcol + r;
                float pv = alpha_p[rn], nv = -alpha_n[rn];
                const float4* wb =
                    reinterpret_cast<const float4*>(Wf + (size_t)rn * K + kt + kc);
                float4 b0 = wb[0], b1 = wb[1];
                float vals[8] = {b0.x, b0.y, b0.z, b0.w, b1.x, b1.y, b1.z, b1.w};
                short8 tb;
#pragma unroll
                for (int e = 0; e < 8; ++e) {
                    float v = vals[e];
                    float ev = v > DELTA ? pv : (v < -DELTA ? nv : 0.0f);
                    tb[e] = f32_to_bf16_bits(ev);
                }
                *reinterpret_cast<short8*>(Bs + chunk * 512 + ln * 8) = tb;
            }
        }
        __syncthreads();

        short8 af[4], bfr[4];
#pragma unroll
        for (int i = 0; i < 4; ++i) {
            int ra = wr * 64 + i * 16 + (ln & 15);
            af[i] = *reinterpret_cast<const short8*>(As + ra * 32 + (ln >> 4) * 8);
            int rb = wc * 64 + i * 16 + (ln & 15);
            bfr[i] = *reinterpret_cast<const short8*>(Bs + rb * 32 + (ln >> 4) * 8);
        }
#pragma unroll
        for (int i = 0; i < 4; ++i)
#pragma unroll
            for (int j = 0; j < 4; ++j)
                acc[i][j] = __builtin_amdgcn_mfma_f32_16x16x32_bf16(
                    af[i], bfr[j], acc[i][j], 0, 0, 0);
        __syncthreads();
    }

#pragma unroll
    for (int j = 0; j < 4; ++j) {
        int col = bcol + wc * 64 + j * 16 + (ln & 15);
        float bv = bias[col];
#pragma unroll
        for (int i = 0; i < 4; ++i) {
            int row0 = brow + wr * 64 + i * 16 + (ln >> 4) * 4;
#pragma unroll
            for (int q = 0; q < 4; ++q) {
                C[(size_t)(row0 + q) * N + col] = acc[i][j][q] + bv;
            }
        }
    }
}

extern "C" void kernel_launch(void* const* d_in, const int* in_sizes, int n_in,
                              void* d_out, int out_size, void* d_ws, size_t ws_size,
                              hipStream_t stream) {
    const float* x  = (const float*)d_in[0];
    const float* w  = (const float*)d_in[1];
    const float* ap = (const float*)d_in[2];
    const float* an = (const float*)d_in[3];
    const float* bs = (const float*)d_in[4];
    float* out = (float*)d_out;

    const int N = in_sizes[2];            // 4096
    const int K = in_sizes[1] / N;        // 4096
    const int M = in_sizes[0] / K;        // 8192

    const size_t needA = (size_t)M * K * 2;
    const size_t needB = (size_t)N * K * 2;

    if (ws_size >= needA + needB) {
        unsigned short* aq = (unsigned short*)d_ws;
        unsigned short* wq = (unsigned short*)((char*)d_ws + needA);
        const int ABLK = 2048, WBLK = 1024;
        quant_ab_kernel<<<ABLK + WBLK, 256, 0, stream>>>(
            x, w, ap, an, aq, wq, K, (long)M * K, (long)N * K, ABLK);
        const bool ok8p = (M % 256 == 0) && (N % 256 == 0) && (K == 4096);
        if (ok8p) {
            dim3 grid(N / 256, M / 256);
            gemm8p<4096><<<grid, 512, 0, stream>>>(aq, wq, bs, out, M, N);
        } else {
            dim3 grid(N / 128, M / 128);
            gemm_tern<0><<<grid, 256, 0, stream>>>(aq, wq, nullptr, nullptr,
                                                   ap, an, bs, out, M, N, K);
        }
    } else {
        dim3 grid(N / 128, M / 128);
        gemm_tern<1><<<grid, 256, 0, stream>>>(nullptr, nullptr, x, w,
                                               ap, an, bs, out, M, N, K);
    }
}

// Round 10
// 196.255 us; speedup vs baseline: 1.7126x; 1.6738x over previous
//
#include <hip/hip_runtime.h>
#include <hip/hip_bf16.h>

#define DELTA 0.05f

typedef __attribute__((ext_vector_type(8))) short short8;
typedef __attribute__((ext_vector_type(4))) float f32x4;
typedef __attribute__((ext_vector_type(4))) int int4v;

__device__ __forceinline__ unsigned short tern_bits(float v) {
    return v > DELTA ? 0x3F80u : (v < -DELTA ? 0xBF80u : 0u);
}

__device__ __forceinline__ short f32_to_bf16_bits(float v) {
    __hip_bfloat16 h = __float2bfloat16(v);
    unsigned short bits;
    __builtin_memcpy(&bits, &h, 2);
    return (short)bits;
}

__device__ __forceinline__ signed char tern_i8(float v) {
    return v > DELTA ? 1 : (v < -DELTA ? -1 : 0);
}

// ---------------- quantize x -> ternary i8 ----------------
__global__ void quant_a8_kernel(const float* __restrict__ x,
                                signed char* __restrict__ out, long total) {
    long idx = ((long)blockIdx.x * blockDim.x + threadIdx.x) * 16;
    long stride = (long)gridDim.x * blockDim.x * 16;
    for (; idx < total; idx += stride) {
        const float4* p = reinterpret_cast<const float4*>(x + idx);
        union { signed char c[16]; int4v v; } r;
#pragma unroll
        for (int q = 0; q < 4; ++q) {
            float4 f = p[q];
            r.c[q * 4 + 0] = tern_i8(f.x);
            r.c[q * 4 + 1] = tern_i8(f.y);
            r.c[q * 4 + 2] = tern_i8(f.z);
            r.c[q * 4 + 3] = tern_i8(f.w);
        }
        *reinterpret_cast<int4v*>(out + idx) = r.v;
    }
}

// ---------------- quantize w_latent -> round(64*w_eff) i8 ----------------
__global__ void quant_w8_kernel(const float* __restrict__ w,
                                const float* __restrict__ ap,
                                const float* __restrict__ an,
                                signed char* __restrict__ out,
                                int K, long total) {
    long idx = ((long)blockIdx.x * blockDim.x + threadIdx.x) * 16;
    long stride = (long)gridDim.x * blockDim.x * 16;
    for (; idx < total; idx += stride) {
        int n = (int)(idx / K);
        float pv = fminf(fmaxf(rintf(64.0f * ap[n]), -127.0f), 127.0f);
        float nv = -fminf(fmaxf(rintf(64.0f * an[n]), -127.0f), 127.0f);
        const float4* p = reinterpret_cast<const float4*>(w + idx);
        union { signed char c[16]; int4v v; } r;
#pragma unroll
        for (int q = 0; q < 4; ++q) {
            float4 f = p[q];
            float vv[4] = {f.x, f.y, f.z, f.w};
#pragma unroll
            for (int e = 0; e < 4; ++e) {
                float v = vv[e];
                float ev = v > DELTA ? pv : (v < -DELTA ? nv : 0.0f);
                r.c[q * 4 + e] = (signed char)(int)ev;
            }
        }
        *reinterpret_cast<int4v*>(out + idx) = r.v;
    }
}

// ================= 256x256 8-phase i8 GEMM (r6 structure, byte-identical) ====
// r6's verified schedule with i8: LDS rows stay 128B (=128 i8 k), same swizzle
// and read offsets; mfma_i32_16x16x64_i8 covers k=64 i8 per instr -> NT and
// phase count HALVE vs bf16. C = i32_acc * (1/64) + bias (W scaled by 64).
// K here is BYTES per row (= elements, i8).
__global__ __launch_bounds__(512, 2) void gemm8p(
    const signed char* __restrict__ A, const signed char* __restrict__ B,
    const float* __restrict__ bias, float* __restrict__ C,
    int M, int N, int K) {
    __shared__ unsigned char As[2 * 256 * 128];
    __shared__ unsigned char Bs[2 * 256 * 128];

    const int tid = threadIdx.x;
    const int wid = tid >> 6;
    const int ln  = tid & 63;
    const int wr  = wid >> 2;   // 0..1
    const int wc  = wid & 3;    // 0..3

    // --- XCD-chunked swizzle (bijective: nwg % 8 == 0 when gridDim.y % 8 == 0)
    int bx = blockIdx.x, by = blockIdx.y;
    if ((gridDim.y & 7) == 0) {
        const int nbx = gridDim.x;
        const int rpx = gridDim.y >> 3;       // rows per XCD chunk
        int bid = by * nbx + bx;
        int xcd = bid & 7;
        int off = bid >> 3;
        by = xcd * rpx + (off % rpx);         // row fastest within chunk
        bx = off / rpx;
    }
    const int brow = by * 256;
    const int bcol = bx * 256;

    const int NT   = K >> 7;    // 128-byte K-tiles
    const int STOT = NT * 4;    // half-tile stream length

    // staging geometry: chunk = 8 rows x 128 B (1 KiB), 2 chunks/wave/half-tile
    const int srow   = ln >> 3;
    const int scol   = ((ln & 7) ^ srow) * 16;  // inverse-swizzled source byte
    const int chunk0 = wid * 2;

    // ds_read geometry (bytes)
    const int lnlo = ln & 15;
    const int swz  = (ln & 7) << 4;
    const int koff = (ln >> 4) * 16;

    int4v acc[8][4] = {};
    int4v bfrag[4][2];
    int s = 0;

    auto STAGE = [&](int si) {
        if (si >= STOT) return;
        int tile = si >> 2, slot = si & 3, buf = tile & 1;
        int kt = tile << 7;
        const signed char* g = (slot >= 2) ? A : B;
        int grow = ((slot >= 2) ? brow : bcol) + (slot & 1) * 128;
        unsigned char* lb = ((slot >= 2) ? As : Bs) + buf * 32768 + (slot & 1) * 16384;
#pragma unroll
        for (int j = 0; j < 2; ++j) {
            int c = chunk0 + j;
            const signed char* src =
                g + (size_t)(grow + c * 8 + srow) * K + kt + scol;
            __builtin_amdgcn_global_load_lds(
                (const __attribute__((address_space(1))) void*)src,
                (__attribute__((address_space(3))) void*)(lb + c * 1024),
                16, 0, 0);
        }
    };

#define PHASE(BUF, Q, FIRST, VMS)                                              \
    {                                                                          \
        const char* Ab = (const char*)As + (BUF) * 32768;                      \
        const char* Bb = (const char*)Bs + (BUF) * 32768;                      \
        int4v afrag[2][2];                                                     \
        _Pragma("unroll")                                                      \
        for (int m2 = 0; m2 < 2; ++m2) {                                       \
            int r = wr * 128 + ((Q) * 2 + m2) * 16 + lnlo;                     \
            _Pragma("unroll")                                                  \
            for (int kk = 0; kk < 2; ++kk)                                     \
                afrag[m2][kk] = *(const int4v*)(Ab + r * 128 +                 \
                                                ((kk * 64 + koff) ^ swz));     \
        }                                                                      \
        if (FIRST) {                                                           \
            _Pragma("unroll")                                                  \
            for (int n = 0; n < 4; ++n) {                                      \
                int r = wc * 64 + n * 16 + lnlo;                               \
                _Pragma("unroll")                                              \
                for (int kk = 0; kk < 2; ++kk)                                 \
                    bfrag[n][kk] = *(const int4v*)(Bb + r * 128 +              \
                                                   ((kk * 64 + koff) ^ swz));  \
            }                                                                  \
        }                                                                      \
        STAGE(s); ++s;                                                         \
        __builtin_amdgcn_s_barrier();                                          \
        asm volatile("s_waitcnt lgkmcnt(0)");                                  \
        __builtin_amdgcn_s_setprio(1);                                         \
        _Pragma("unroll")                                                      \
        for (int m2 = 0; m2 < 2; ++m2)                                         \
            _Pragma("unroll")                                                  \
            for (int n = 0; n < 4; ++n)                                        \
                _Pragma("unroll")                                              \
                for (int kk = 0; kk < 2; ++kk)                                 \
                    acc[(Q) * 2 + m2][n] =                                     \
                        __builtin_amdgcn_mfma_i32_16x16x64_i8(                 \
                            afrag[m2][kk], bfrag[n][kk],                       \
                            acc[(Q) * 2 + m2][n], 0, 0, 0);                    \
        __builtin_amdgcn_s_setprio(0);                                         \
        VMS;                                                                   \
        __builtin_amdgcn_s_barrier();                                          \
    }

    // prologue: t0 fully (4 ht) + 3 ht of t1; gate t0
    for (int i = 0; i < 7; ++i) { STAGE(s); ++s; }
    asm volatile("s_waitcnt vmcnt(6)" ::: "memory");
    __builtin_amdgcn_s_barrier();

    const int NP = NT / 2 - 1;
#pragma unroll 1
    for (int p = 0; p < NP; ++p) {
        PHASE(0, 0, true,  (void)0)
        PHASE(0, 1, false, (void)0)
        PHASE(0, 2, false, (void)0)
        PHASE(0, 3, false, asm volatile("s_waitcnt vmcnt(6)" ::: "memory"))
        PHASE(1, 0, true,  (void)0)
        PHASE(1, 1, false, (void)0)
        PHASE(1, 2, false, (void)0)
        PHASE(1, 3, false, asm volatile("s_waitcnt vmcnt(6)" ::: "memory"))
    }
    // epilogue tiles NT-2 (buf0), NT-1 (buf1)
    PHASE(0, 0, true,  (void)0)
    PHASE(0, 1, false, (void)0)
    PHASE(0, 2, false, (void)0)
    PHASE(0, 3, false, asm volatile("s_waitcnt vmcnt(0)" ::: "memory"))
    PHASE(1, 0, true,  (void)0)
    PHASE(1, 1, false, (void)0)
    PHASE(1, 2, false, (void)0)
    PHASE(1, 3, false, (void)0)
#undef PHASE

    // C write + bias. D layout: col=lane&15, row=(lane>>4)*4+q (shape-determined)
    const float s64 = 0.015625f;  // 1/64
#pragma unroll
    for (int n = 0; n < 4; ++n) {
        int col = bcol + wc * 64 + n * 16 + lnlo;
        float bv = bias[col];
#pragma unroll
        for (int m = 0; m < 8; ++m) {
            int row0 = brow + wr * 128 + m * 16 + (ln >> 4) * 4;
#pragma unroll
            for (int q = 0; q < 4; ++q)
                C[(size_t)(row0 + q) * N + col] =
                    (float)acc[m][n][q] * s64 + bv;
        }
    }
}

// ---------------- bf16 quant + fallback 128^2 GEMM (round-1, known-good) ----
__global__ void quant_a_kernel(const float* __restrict__ x,
                               unsigned short* __restrict__ out, long total) {
    long idx = ((long)blockIdx.x * blockDim.x + threadIdx.x) * 8;
    long stride = (long)gridDim.x * blockDim.x * 8;
    for (; idx < total; idx += stride) {
        const float4* p = reinterpret_cast<const float4*>(x + idx);
        float4 v0 = p[0], v1 = p[1];
        short8 r;
        r[0] = (short)tern_bits(v0.x); r[1] = (short)tern_bits(v0.y);
        r[2] = (short)tern_bits(v0.z); r[3] = (short)tern_bits(v0.w);
        r[4] = (short)tern_bits(v1.x); r[5] = (short)tern_bits(v1.y);
        r[6] = (short)tern_bits(v1.z); r[7] = (short)tern_bits(v1.w);
        *reinterpret_cast<short8*>(out + idx) = r;
    }
}

__global__ void quant_w_kernel(const float* __restrict__ w,
                               const float* __restrict__ ap,
                               const float* __restrict__ an,
                               unsigned short* __restrict__ out,
                               int K, long total) {
    long idx = ((long)blockIdx.x * blockDim.x + threadIdx.x) * 8;
    long stride = (long)gridDim.x * blockDim.x * 8;
    for (; idx < total; idx += stride) {
        int n = (int)(idx / K);
        float pv = ap[n], nv = -an[n];
        const float4* p = reinterpret_cast<const float4*>(w + idx);
        float4 v0 = p[0], v1 = p[1];
        float vals[8] = {v0.x, v0.y, v0.z, v0.w, v1.x, v1.y, v1.z, v1.w};
        short8 r;
#pragma unroll
        for (int e = 0; e < 8; ++e) {
            float v = vals[e];
            float ev = v > DELTA ? pv : (v < -DELTA ? nv : 0.0f);
            r[e] = f32_to_bf16_bits(ev);
        }
        *reinterpret_cast<short8*>(out + idx) = r;
    }
}

template <int MODE>
__global__ __launch_bounds__(256) void gemm_tern(
    const unsigned short* __restrict__ A, const unsigned short* __restrict__ B,
    const float* __restrict__ Xf, const float* __restrict__ Wf,
    const float* __restrict__ alpha_p, const float* __restrict__ alpha_n,
    const float* __restrict__ bias, float* __restrict__ C,
    int M, int N, int K) {
    __shared__ unsigned short As[128 * 32];
    __shared__ unsigned short Bs[128 * 32];

    const int tid = threadIdx.x;
    const int wv = tid >> 6;
    const int ln = tid & 63;
    const int brow = blockIdx.y * 128;
    const int bcol = blockIdx.x * 128;
    const int wr = wv >> 1;
    const int wc = wv & 1;

    f32x4 acc[4][4] = {};

    for (int kt = 0; kt < K; kt += 32) {
        if (MODE == 0) {
#pragma unroll
            for (int j = 0; j < 2; ++j) {
                int chunk = wv * 2 + j;
                int r = chunk * 16 + (ln >> 2);
                int kc = (ln & 3) * 8;
                const unsigned short* ga = A + (size_t)(brow + r) * K + kt + kc;
                const unsigned short* gb = B + (size_t)(bcol + r) * K + kt + kc;
                __builtin_amdgcn_global_load_lds(
                    (const __attribute__((address_space(1))) void*)ga,
                    (__attribute__((address_space(3))) void*)(As + chunk * 512),
                    16, 0, 0);
                __builtin_amdgcn_global_load_lds(
                    (const __attribute__((address_space(1))) void*)gb,
                    (__attribute__((address_space(3))) void*)(Bs + chunk * 512),
                    16, 0, 0);
            }
        } else {
#pragma unroll
            for (int j = 0; j < 2; ++j) {
                int chunk = wv * 2 + j;
                int r = chunk * 16 + (ln >> 2);
                int kc = (ln & 3) * 8;
                const float4* xa =
                    reinterpret_cast<const float4*>(Xf + (size_t)(brow + r) * K + kt + kc);
                float4 a0 = xa[0], a1 = xa[1];
                short8 ta;
                ta[0] = (short)tern_bits(a0.x); ta[1] = (short)tern_bits(a0.y);
                ta[2] = (short)tern_bits(a0.z); ta[3] = (short)tern_bits(a0.w);
                ta[4] = (short)tern_bits(a1.x); ta[5] = (short)tern_bits(a1.y);
                ta[6] = (short)tern_bits(a1.z); ta[7] = (short)tern_bits(a1.w);
                *reinterpret_cast<short8*>(As + chunk * 512 + ln * 8) = ta;

                int rn = bcol + r;
                float pv = alpha_p[rn], nv = -alpha_n[rn];
                const float4* wb =
                    reinterpret_cast<const float4*>(Wf + (size_t)rn * K + kt + kc);
                float4 b0 = wb[0], b1 = wb[1];
                float vals[8] = {b0.x, b0.y, b0.z, b0.w, b1.x, b1.y, b1.z, b1.w};
                short8 tb;
#pragma unroll
                for (int e = 0; e < 8; ++e) {
                    float v = vals[e];
                    float ev = v > DELTA ? pv : (v < -DELTA ? nv : 0.0f);
                    tb[e] = f32_to_bf16_bits(ev);
                }
                *reinterpret_cast<short8*>(Bs + chunk * 512 + ln * 8) = tb;
            }
        }
        __syncthreads();

        short8 af[4], bfr[4];
#pragma unroll
        for (int i = 0; i < 4; ++i) {
            int ra = wr * 64 + i * 16 + (ln & 15);
            af[i] = *reinterpret_cast<const short8*>(As + ra * 32 + (ln >> 4) * 8);
            int rb = wc * 64 + i * 16 + (ln & 15);
            bfr[i] = *reinterpret_cast<const short8*>(Bs + rb * 32 + (ln >> 4) * 8);
        }
#pragma unroll
        for (int i = 0; i < 4; ++i)
#pragma unroll
            for (int j = 0; j < 4; ++j)
                acc[i][j] = __builtin_amdgcn_mfma_f32_16x16x32_bf16(
                    af[i], bfr[j], acc[i][j], 0, 0, 0);
        __syncthreads();
    }

#pragma unroll
    for (int j = 0; j < 4; ++j) {
        int col = bcol + wc * 64 + j * 16 + (ln & 15);
        float bv = bias[col];
#pragma unroll
        for (int i = 0; i < 4; ++i) {
            int row0 = brow + wr * 64 + i * 16 + (ln >> 4) * 4;
#pragma unroll
            for (int q = 0; q < 4; ++q) {
                C[(size_t)(row0 + q) * N + col] = acc[i][j][q] + bv;
            }
        }
    }
}

extern "C" void kernel_launch(void* const* d_in, const int* in_sizes, int n_in,
                              void* d_out, int out_size, void* d_ws, size_t ws_size,
                              hipStream_t stream) {
    const float* x  = (const float*)d_in[0];
    const float* w  = (const float*)d_in[1];
    const float* ap = (const float*)d_in[2];
    const float* an = (const float*)d_in[3];
    const float* bs = (const float*)d_in[4];
    float* out = (float*)d_out;

    const int N = in_sizes[2];            // 4096
    const int K = in_sizes[1] / N;        // 4096
    const int M = in_sizes[0] / K;        // 8192

    const bool ok8p = (M % 256 == 0) && (N % 256 == 0) && (K % 256 == 0);
    const size_t needA8 = (size_t)M * K;
    const size_t needB8 = (size_t)N * K;

    if (ok8p && ws_size >= needA8 + needB8) {
        signed char* aq = (signed char*)d_ws;
        signed char* wq = (signed char*)d_ws + needA8;
        quant_a8_kernel<<<2048, 256, 0, stream>>>(x, aq, (long)M * K);
        quant_w8_kernel<<<1024, 256, 0, stream>>>(w, ap, an, wq, K, (long)N * K);
        dim3 grid(N / 256, M / 256);
        gemm8p<<<grid, 512, 0, stream>>>(aq, wq, bs, out, M, N, K);
    } else if (ws_size >= (size_t)(M + N) * K * 2) {
        unsigned short* aq = (unsigned short*)d_ws;
        unsigned short* wq = (unsigned short*)((char*)d_ws + (size_t)M * K * 2);
        quant_a_kernel<<<2048, 256, 0, stream>>>(x, aq, (long)M * K);
        quant_w_kernel<<<2048, 256, 0, stream>>>(w, ap, an, wq, K, (long)N * K);
        dim3 grid(N / 128, M / 128);
        gemm_tern<0><<<grid, 256, 0, stream>>>(aq, wq, nullptr, nullptr,
                                               ap, an, bs, out, M, N, K);
    } else {
        dim3 grid(N / 128, M / 128);
        gemm_tern<1><<<grid, 256, 0, stream>>>(nullptr, nullptr, x, w,
                                               ap, an, bs, out, M, N, K);
    }
}

// Round 11
// 192.125 us; speedup vs baseline: 1.7494x; 1.0215x over previous
//
#include <hip/hip_runtime.h>
#include <hip/hip_bf16.h>

#define DELTA 0.05f

typedef __attribute__((ext_vector_type(8))) short short8;
typedef __attribute__((ext_vector_type(4))) float f32x4;
typedef __attribute__((ext_vector_type(4))) int int4v;

__device__ __forceinline__ unsigned short tern_bits(float v) {
    return v > DELTA ? 0x3F80u : (v < -DELTA ? 0xBF80u : 0u);
}

__device__ __forceinline__ short f32_to_bf16_bits(float v) {
    __hip_bfloat16 h = __float2bfloat16(v);
    unsigned short bits;
    __builtin_memcpy(&bits, &h, 2);
    return (short)bits;
}

__device__ __forceinline__ signed char tern_i8(float v) {
    return v > DELTA ? 1 : (v < -DELTA ? -1 : 0);
}

// ------- fused quantize: blocks [0,ABLK) do x->i8, rest do w->i8*64 ---------
__global__ void quant_ab8_kernel(const float* __restrict__ x,
                                 const float* __restrict__ w,
                                 const float* __restrict__ ap,
                                 const float* __restrict__ an,
                                 signed char* __restrict__ aq,
                                 signed char* __restrict__ wq,
                                 int K, long totalA, long totalW, int ABLK) {
    if ((int)blockIdx.x < ABLK) {
        long idx = ((long)blockIdx.x * blockDim.x + threadIdx.x) * 16;
        long stride = (long)ABLK * blockDim.x * 16;
        for (; idx < totalA; idx += stride) {
            const float4* p = reinterpret_cast<const float4*>(x + idx);
            union { signed char c[16]; int4v v; } r;
#pragma unroll
            for (int q = 0; q < 4; ++q) {
                float4 f = p[q];
                r.c[q * 4 + 0] = tern_i8(f.x);
                r.c[q * 4 + 1] = tern_i8(f.y);
                r.c[q * 4 + 2] = tern_i8(f.z);
                r.c[q * 4 + 3] = tern_i8(f.w);
            }
            *reinterpret_cast<int4v*>(aq + idx) = r.v;
        }
    } else {
        int wb = (int)blockIdx.x - ABLK;
        int nwb = (int)gridDim.x - ABLK;
        long idx = ((long)wb * blockDim.x + threadIdx.x) * 16;
        long stride = (long)nwb * blockDim.x * 16;
        for (; idx < totalW; idx += stride) {
            int n = (int)(idx / K);
            float pv = fminf(fmaxf(rintf(64.0f * ap[n]), -127.0f), 127.0f);
            float nv = -fminf(fmaxf(rintf(64.0f * an[n]), -127.0f), 127.0f);
            const float4* p = reinterpret_cast<const float4*>(w + idx);
            union { signed char c[16]; int4v v; } r;
#pragma unroll
            for (int q = 0; q < 4; ++q) {
                float4 f = p[q];
                float vv[4] = {f.x, f.y, f.z, f.w};
#pragma unroll
                for (int e = 0; e < 4; ++e) {
                    float v = vv[e];
                    float ev = v > DELTA ? pv : (v < -DELTA ? nv : 0.0f);
                    r.c[q * 4 + e] = (signed char)(int)ev;
                }
            }
            *reinterpret_cast<int4v*>(wq + idx) = r.v;
        }
    }
}

// ================= 256x256 8-phase i8 GEMM (r10, minus per-phase lgkm drain) =
// r10 verbatim except the explicit `s_waitcnt lgkmcnt(0)` inside PHASE is
// REMOVED: the compiler's dependency-counted lgkm waits let the first MFMAs
// start while the remaining ds_reads are in flight (partial LDS||MFMA overlap
// within each phase). Read placement, barriers, and vmcnt gates unchanged.
__global__ __launch_bounds__(512, 2) void gemm8p(
    const signed char* __restrict__ A, const signed char* __restrict__ B,
    const float* __restrict__ bias, float* __restrict__ C,
    int M, int N, int K) {
    __shared__ unsigned char As[2 * 256 * 128];
    __shared__ unsigned char Bs[2 * 256 * 128];

    const int tid = threadIdx.x;
    const int wid = tid >> 6;
    const int ln  = tid & 63;
    const int wr  = wid >> 2;   // 0..1
    const int wc  = wid & 3;    // 0..3

    // --- XCD-chunked swizzle (bijective: nwg % 8 == 0 when gridDim.y % 8 == 0)
    int bx = blockIdx.x, by = blockIdx.y;
    if ((gridDim.y & 7) == 0) {
        const int nbx = gridDim.x;
        const int rpx = gridDim.y >> 3;       // rows per XCD chunk
        int bid = by * nbx + bx;
        int xcd = bid & 7;
        int off = bid >> 3;
        by = xcd * rpx + (off % rpx);         // row fastest within chunk
        bx = off / rpx;
    }
    const int brow = by * 256;
    const int bcol = bx * 256;

    const int NT   = K >> 7;    // 128-byte K-tiles
    const int STOT = NT * 4;    // half-tile stream length

    // staging geometry: chunk = 8 rows x 128 B (1 KiB), 2 chunks/wave/half-tile
    const int srow   = ln >> 3;
    const int scol   = ((ln & 7) ^ srow) * 16;  // inverse-swizzled source byte
    const int chunk0 = wid * 2;

    // ds_read geometry (bytes)
    const int lnlo = ln & 15;
    const int swz  = (ln & 7) << 4;
    const int koff = (ln >> 4) * 16;

    int4v acc[8][4] = {};
    int4v bfrag[4][2];
    int s = 0;

    auto STAGE = [&](int si) {
        if (si >= STOT) return;
        int tile = si >> 2, slot = si & 3, buf = tile & 1;
        int kt = tile << 7;
        const signed char* g = (slot >= 2) ? A : B;
        int grow = ((slot >= 2) ? brow : bcol) + (slot & 1) * 128;
        unsigned char* lb = ((slot >= 2) ? As : Bs) + buf * 32768 + (slot & 1) * 16384;
#pragma unroll
        for (int j = 0; j < 2; ++j) {
            int c = chunk0 + j;
            const signed char* src =
                g + (size_t)(grow + c * 8 + srow) * K + kt + scol;
            __builtin_amdgcn_global_load_lds(
                (const __attribute__((address_space(1))) void*)src,
                (__attribute__((address_space(3))) void*)(lb + c * 1024),
                16, 0, 0);
        }
    };

#define PHASE(BUF, Q, FIRST, VMS)                                              \
    {                                                                          \
        const char* Ab = (const char*)As + (BUF) * 32768;                      \
        const char* Bb = (const char*)Bs + (BUF) * 32768;                      \
        int4v afrag[2][2];                                                     \
        _Pragma("unroll")                                                      \
        for (int m2 = 0; m2 < 2; ++m2) {                                       \
            int r = wr * 128 + ((Q) * 2 + m2) * 16 + lnlo;                     \
            _Pragma("unroll")                                                  \
            for (int kk = 0; kk < 2; ++kk)                                     \
                afrag[m2][kk] = *(const int4v*)(Ab + r * 128 +                 \
                                                ((kk * 64 + koff) ^ swz));     \
        }                                                                      \
        if (FIRST) {                                                           \
            _Pragma("unroll")                                                  \
            for (int n = 0; n < 4; ++n) {                                      \
                int r = wc * 64 + n * 16 + lnlo;                               \
                _Pragma("unroll")                                              \
                for (int kk = 0; kk < 2; ++kk)                                 \
                    bfrag[n][kk] = *(const int4v*)(Bb + r * 128 +              \
                                                   ((kk * 64 + koff) ^ swz));  \
            }                                                                  \
        }                                                                      \
        STAGE(s); ++s;                                                         \
        __builtin_amdgcn_s_barrier();                                          \
        __builtin_amdgcn_s_setprio(1);                                         \
        _Pragma("unroll")                                                      \
        for (int m2 = 0; m2 < 2; ++m2)                                         \
            _Pragma("unroll")                                                  \
            for (int n = 0; n < 4; ++n)                                        \
                _Pragma("unroll")                                              \
                for (int kk = 0; kk < 2; ++kk)                                 \
                    acc[(Q) * 2 + m2][n] =                                     \
                        __builtin_amdgcn_mfma_i32_16x16x64_i8(                 \
                            afrag[m2][kk], bfrag[n][kk],                       \
                            acc[(Q) * 2 + m2][n], 0, 0, 0);                    \
        __builtin_amdgcn_s_setprio(0);                                         \
        VMS;                                                                   \
        __builtin_amdgcn_s_barrier();                                          \
    }

    // prologue: t0 fully (4 ht) + 3 ht of t1; gate t0
    for (int i = 0; i < 7; ++i) { STAGE(s); ++s; }
    asm volatile("s_waitcnt vmcnt(6)" ::: "memory");
    __builtin_amdgcn_s_barrier();

    const int NP = NT / 2 - 1;
#pragma unroll 1
    for (int p = 0; p < NP; ++p) {
        PHASE(0, 0, true,  (void)0)
        PHASE(0, 1, false, (void)0)
        PHASE(0, 2, false, (void)0)
        PHASE(0, 3, false, asm volatile("s_waitcnt vmcnt(6)" ::: "memory"))
        PHASE(1, 0, true,  (void)0)
        PHASE(1, 1, false, (void)0)
        PHASE(1, 2, false, (void)0)
        PHASE(1, 3, false, asm volatile("s_waitcnt vmcnt(6)" ::: "memory"))
    }
    // epilogue tiles NT-2 (buf0), NT-1 (buf1)
    PHASE(0, 0, true,  (void)0)
    PHASE(0, 1, false, (void)0)
    PHASE(0, 2, false, (void)0)
    PHASE(0, 3, false, asm volatile("s_waitcnt vmcnt(0)" ::: "memory"))
    PHASE(1, 0, true,  (void)0)
    PHASE(1, 1, false, (void)0)
    PHASE(1, 2, false, (void)0)
    PHASE(1, 3, false, (void)0)
#undef PHASE

    // C write + bias. D layout: col=lane&15, row=(lane>>4)*4+q (shape-determined)
    const float s64 = 0.015625f;  // 1/64
#pragma unroll
    for (int n = 0; n < 4; ++n) {
        int col = bcol + wc * 64 + n * 16 + lnlo;
        float bv = bias[col];
#pragma unroll
        for (int m = 0; m < 8; ++m) {
            int row0 = brow + wr * 128 + m * 16 + (ln >> 4) * 4;
#pragma unroll
            for (int q = 0; q < 4; ++q)
                C[(size_t)(row0 + q) * N + col] =
                    (float)acc[m][n][q] * s64 + bv;
        }
    }
}

// ---------------- bf16 quant + fallback 128^2 GEMM (round-1, known-good) ----
__global__ void quant_a_kernel(const float* __restrict__ x,
                               unsigned short* __restrict__ out, long total) {
    long idx = ((long)blockIdx.x * blockDim.x + threadIdx.x) * 8;
    long stride = (long)gridDim.x * blockDim.x * 8;
    for (; idx < total; idx += stride) {
        const float4* p = reinterpret_cast<const float4*>(x + idx);
        float4 v0 = p[0], v1 = p[1];
        short8 r;
        r[0] = (short)tern_bits(v0.x); r[1] = (short)tern_bits(v0.y);
        r[2] = (short)tern_bits(v0.z); r[3] = (short)tern_bits(v0.w);
        r[4] = (short)tern_bits(v1.x); r[5] = (short)tern_bits(v1.y);
        r[6] = (short)tern_bits(v1.z); r[7] = (short)tern_bits(v1.w);
        *reinterpret_cast<short8*>(out + idx) = r;
    }
}

__global__ void quant_w_kernel(const float* __restrict__ w,
                               const float* __restrict__ ap,
                               const float* __restrict__ an,
                               unsigned short* __restrict__ out,
                               int K, long total) {
    long idx = ((long)blockIdx.x * blockDim.x + threadIdx.x) * 8;
    long stride = (long)gridDim.x * blockDim.x * 8;
    for (; idx < total; idx += stride) {
        int n = (int)(idx / K);
        float pv = ap[n], nv = -an[n];
        const float4* p = reinterpret_cast<const float4*>(w + idx);
        float4 v0 = p[0], v1 = p[1];
        float vals[8] = {v0.x, v0.y, v0.z, v0.w, v1.x, v1.y, v1.z, v1.w};
        short8 r;
#pragma unroll
        for (int e = 0; e < 8; ++e) {
            float v = vals[e];
            float ev = v > DELTA ? pv : (v < -DELTA ? nv : 0.0f);
            r[e] = f32_to_bf16_bits(ev);
        }
        *reinterpret_cast<short8*>(out + idx) = r;
    }
}

template <int MODE>
__global__ __launch_bounds__(256) void gemm_tern(
    const unsigned short* __restrict__ A, const unsigned short* __restrict__ B,
    const float* __restrict__ Xf, const float* __restrict__ Wf,
    const float* __restrict__ alpha_p, const float* __restrict__ alpha_n,
    const float* __restrict__ bias, float* __restrict__ C,
    int M, int N, int K) {
    __shared__ unsigned short As[128 * 32];
    __shared__ unsigned short Bs[128 * 32];

    const int tid = threadIdx.x;
    const int wv = tid >> 6;
    const int ln = tid & 63;
    const int brow = blockIdx.y * 128;
    const int bcol = blockIdx.x * 128;
    const int wr = wv >> 1;
    const int wc = wv & 1;

    f32x4 acc[4][4] = {};

    for (int kt = 0; kt < K; kt += 32) {
        if (MODE == 0) {
#pragma unroll
            for (int j = 0; j < 2; ++j) {
                int chunk = wv * 2 + j;
                int r = chunk * 16 + (ln >> 2);
                int kc = (ln & 3) * 8;
                const unsigned short* ga = A + (size_t)(brow + r) * K + kt + kc;
                const unsigned short* gb = B + (size_t)(bcol + r) * K + kt + kc;
                __builtin_amdgcn_global_load_lds(
                    (const __attribute__((address_space(1))) void*)ga,
                    (__attribute__((address_space(3))) void*)(As + chunk * 512),
                    16, 0, 0);
                __builtin_amdgcn_global_load_lds(
                    (const __attribute__((address_space(1))) void*)gb,
                    (__attribute__((address_space(3))) void*)(Bs + chunk * 512),
                    16, 0, 0);
            }
        } else {
#pragma unroll
            for (int j = 0; j < 2; ++j) {
                int chunk = wv * 2 + j;
                int r = chunk * 16 + (ln >> 2);
                int kc = (ln & 3) * 8;
                const float4* xa =
                    reinterpret_cast<const float4*>(Xf + (size_t)(brow + r) * K + kt + kc);
                float4 a0 = xa[0], a1 = xa[1];
                short8 ta;
                ta[0] = (short)tern_bits(a0.x); ta[1] = (short)tern_bits(a0.y);
                ta[2] = (short)tern_bits(a0.z); ta[3] = (short)tern_bits(a0.w);
                ta[4] = (short)tern_bits(a1.x); ta[5] = (short)tern_bits(a1.y);
                ta[6] = (short)tern_bits(a1.z); ta[7] = (short)tern_bits(a1.w);
                *reinterpret_cast<short8*>(As + chunk * 512 + ln * 8) = ta;

                int rn = bcol + r;
                float pv = alpha_p[rn], nv = -alpha_n[rn];
                const float4* wb =
                    reinterpret_cast<const float4*>(Wf + (size_t)rn * K + kt + kc);
                float4 b0 = wb[0], b1 = wb[1];
                float vals[8] = {b0.x, b0.y, b0.z, b0.w, b1.x, b1.y, b1.z, b1.w};
                short8 tb;
#pragma unroll
                for (int e = 0; e < 8; ++e) {
                    float v = vals[e];
                    float ev = v > DELTA ? pv : (v < -DELTA ? nv : 0.0f);
                    tb[e] = f32_to_bf16_bits(ev);
                }
                *reinterpret_cast<short8*>(Bs + chunk * 512 + ln * 8) = tb;
            }
        }
        __syncthreads();

        short8 af[4], bfr[4];
#pragma unroll
        for (int i = 0; i < 4; ++i) {
            int ra = wr * 64 + i * 16 + (ln & 15);
            af[i] = *reinterpret_cast<const short8*>(As + ra * 32 + (ln >> 4) * 8);
            int rb = wc * 64 + i * 16 + (ln & 15);
            bfr[i] = *reinterpret_cast<const short8*>(Bs + rb * 32 + (ln >> 4) * 8);
        }
#pragma unroll
        for (int i = 0; i < 4; ++i)
#pragma unroll
            for (int j = 0; j < 4; ++j)
                acc[i][j] = __builtin_amdgcn_mfma_f32_16x16x32_bf16(
                    af[i], bfr[j], acc[i][j], 0, 0, 0);
        __syncthreads();
    }

#pragma unroll
    for (int j = 0; j < 4; ++j) {
        int col = bcol + wc * 64 + j * 16 + (ln & 15);
        float bv = bias[col];
#pragma unroll
        for (int i = 0; i < 4; ++i) {
            int row0 = brow + wr * 64 + i * 16 + (ln >> 4) * 4;
#pragma unroll
            for (int q = 0; q < 4; ++q) {
                C[(size_t)(row0 + q) * N + col] = acc[i][j][q] + bv;
            }
        }
    }
}

extern "C" void kernel_launch(void* const* d_in, const int* in_sizes, int n_in,
                              void* d_out, int out_size, void* d_ws, size_t ws_size,
                              hipStream_t stream) {
    const float* x  = (const float*)d_in[0];
    const float* w  = (const float*)d_in[1];
    const float* ap = (const float*)d_in[2];
    const float* an = (const float*)d_in[3];
    const float* bs = (const float*)d_in[4];
    float* out = (float*)d_out;

    const int N = in_sizes[2];            // 4096
    const int K = in_sizes[1] / N;        // 4096
    const int M = in_sizes[0] / K;        // 8192

    const bool ok8p = (M % 256 == 0) && (N % 256 == 0) && (K % 256 == 0);
    const size_t needA8 = (size_t)M * K;
    const size_t needB8 = (size_t)N * K;

    if (ok8p && ws_size >= needA8 + needB8) {
        signed char* aq = (signed char*)d_ws;
        signed char* wq = (signed char*)d_ws + needA8;
        const int ABLK = 2048, WBLK = 1024;
        quant_ab8_kernel<<<ABLK + WBLK, 256, 0, stream>>>(
            x, w, ap, an, aq, wq, K, (long)M * K, (long)N * K, ABLK);
        dim3 grid(N / 256, M / 256);
        gemm8p<<<grid, 512, 0, stream>>>(aq, wq, bs, out, M, N, K);
    } else if (ws_size >= (size_t)(M + N) * K * 2) {
        unsigned short* aq = (unsigned short*)d_ws;
        unsigned short* wq = (unsigned short*)((char*)d_ws + (size_t)M * K * 2);
        quant_a_kernel<<<2048, 256, 0, stream>>>(x, aq, (long)M * K);
        quant_w_kernel<<<2048, 256, 0, stream>>>(w, ap, an, wq, K, (long)N * K);
        dim3 grid(N / 128, M / 128);
        gemm_tern<0><<<grid, 256, 0, stream>>>(aq, wq, nullptr, nullptr,
                                               ap, an, bs, out, M, N, K);
    } else {
        dim3 grid(N / 128, M / 128);
        gemm_tern<1><<<grid, 256, 0, stream>>>(nullptr, nullptr, x, w,
                                               ap, an, bs, out, M, N, K);
    }
}